// Round 9
// baseline (341.994 us; speedup 1.0000x reference)
//
#include <hip/hip_runtime.h>
#include <hip/hip_bf16.h>

#define NT 1024     // tokens (B*S)
#define HD 1024     // hidden
#define ED 1024     // expert inner dim
#define F2D 2048    // 2*E (interleaved gate/up)
#define NEXPERT 16
#define GROWS 2304  // compacted rows (2048) + tile slack
#define ALPHA_C 1.702f
#define LIMIT_C 7.0f

typedef float f32x4 __attribute__((ext_vector_type(4)));
typedef float fv4 __attribute__((ext_vector_type(4)));
typedef short short8 __attribute__((ext_vector_type(8)));
typedef unsigned int u32x4 __attribute__((ext_vector_type(4)));

__device__ __forceinline__ unsigned short f2bf(float x) {
  union { float f; unsigned int u; } v; v.f = x;
  unsigned int r = v.u + 0x7FFFu + ((v.u >> 16) & 1u);
  return (unsigned short)(r >> 16);
}
__device__ __forceinline__ unsigned int pk2(float lo, float hi) {
  return (unsigned int)f2bf(lo) | ((unsigned int)f2bf(hi) << 16);
}
// non-temporal float4 load (weights: stream, don't cache)
__device__ __forceinline__ fv4 ldnt4(const float* p) {
  return __builtin_nontemporal_load((const fv4*)p);
}
// async global->LDS, 16B per lane; LDS dest = wave-uniform base + lane*16
__device__ __forceinline__ void async16(const void* g, void* l) {
  __builtin_amdgcn_global_load_lds((const __attribute__((address_space(1))) void*)g,
                                   (__attribute__((address_space(3))) void*)l, 16, 0, 0);
}

// in-quad 4x4 transpose (XOR network via DPP quad_perm) + b128 LDS store.
// requires: b0,b1 (fv4 weight rows k=2*kpair, 2*kpair+1), sub = lane&3 in scope.
// verified correct rounds 4-8.
#define BT_TRANSPOSE_STORE(DST)                                                         \
  {                                                                                     \
    unsigned int w0p = pk2(b0[0], b1[0]);                                               \
    unsigned int w1p = pk2(b0[1], b1[1]);                                               \
    unsigned int w2p = pk2(b0[2], b1[2]);                                               \
    unsigned int w3p = pk2(b0[3], b1[3]);                                               \
    unsigned int X0 = sub == 0 ? w0p : sub == 1 ? w1p : sub == 2 ? w2p : w3p;           \
    unsigned int X1 = sub == 0 ? w1p : sub == 1 ? w0p : sub == 2 ? w3p : w2p;           \
    unsigned int X2 = sub == 0 ? w2p : sub == 1 ? w3p : sub == 2 ? w0p : w1p;           \
    unsigned int X3 = sub == 0 ? w3p : sub == 1 ? w2p : sub == 2 ? w1p : w0p;           \
    unsigned int r0 = X0;                                                               \
    unsigned int r1 = (unsigned int)__builtin_amdgcn_update_dpp((int)X1, (int)X1, 0xB1, 0xF, 0xF, 0); \
    unsigned int r2 = (unsigned int)__builtin_amdgcn_update_dpp((int)X2, (int)X2, 0x4E, 0xF, 0xF, 0); \
    unsigned int r3 = (unsigned int)__builtin_amdgcn_update_dpp((int)X3, (int)X3, 0x1B, 0xF, 0xF, 0); \
    u32x4 tt;                                                                           \
    tt[0] = sub == 0 ? r0 : sub == 1 ? r1 : sub == 2 ? r2 : r3;                         \
    tt[1] = sub == 0 ? r1 : sub == 1 ? r0 : sub == 2 ? r3 : r2;                         \
    tt[2] = sub == 0 ? r2 : sub == 1 ? r3 : sub == 2 ? r0 : r1;                         \
    tt[3] = sub == 0 ? r3 : sub == 1 ? r2 : sub == 2 ? r1 : r0;                         \
    *(u32x4*)(DST) = tt;                                                                \
  }

// ---------------- router: 4 waves/token; partial logits per wave, LDS reduce, redundant top-2 ----------------
__global__ __launch_bounds__(256) void k_router(const float* __restrict__ x,
                                                const float* __restrict__ Wg,
                                                const float* __restrict__ bg,
                                                const float* __restrict__ bd,
                                                int* __restrict__ e01,
                                                float* __restrict__ w0f,
                                                float* __restrict__ w1f,
                                                unsigned short* __restrict__ Xbf,
                                                float* __restrict__ out) {
  const int t = blockIdx.x;
  const int tid = threadIdx.x;     // 0..255
  const int w = tid >> 6;          // wave 0..3 (quarter of HD)
  const int l = tid & 63;
  const float4* x4 = (const float4*)(x + (size_t)t * HD);
  {
    float4 v = x4[tid];
    unsigned int* dst = (unsigned int*)(Xbf + (size_t)t * HD + tid * 4);
    dst[0] = pk2(v.x, v.y); dst[1] = pk2(v.z, v.w);
  }
  const int e = l & 15, qq = l >> 4;
  const float4* wg4 = (const float4*)(Wg + (size_t)e * HD);
  float s = 0.f;
#pragma unroll 4
  for (int j = 0; j < 16; ++j) {
    const int idx = w * 64 + qq + 4 * j;
    float4 a = x4[idx], b = wg4[idx];
    s += a.x * b.x + a.y * b.y + a.z * b.z + a.w * b.w;
  }
  s += __shfl_xor(s, 16);
  s += __shfl_xor(s, 32);
  __shared__ float slog[4][16];
  if (l < 16) slog[w][e] = s;
  __syncthreads();
  float v0 = -1e30f, v1 = -1e30f; int i0 = 0, i1 = 0;
  for (int k2 = 0; k2 < 16; ++k2) {
    float lv = slog[0][k2] + slog[1][k2] + slog[2][k2] + slog[3][k2] + bg[k2];
    if (lv > v0) { v1 = v0; i1 = i0; v0 = lv; i0 = k2; }
    else if (lv > v1) { v1 = lv; i1 = k2; }
  }
  const float w0 = 1.f / (1.f + __expf(v1 - v0));
  const float w1 = 1.f - w0;
  if (tid == 0) {
    e01[t] = i0 | (i1 << 8);
    w0f[t] = w0;
    w1f[t] = w1;
  }
  const float4* bd0 = (const float4*)(bd + (size_t)i0 * HD);
  const float4* bd1 = (const float4*)(bd + (size_t)i1 * HD);
  float4 a = bd0[tid], b = bd1[tid];
  float4 r;
  r.x = w0 * a.x + w1 * b.x;
  r.y = w0 * a.y + w1 * b.y;
  r.z = w0 * a.z + w1 * b.z;
  r.w = w0 * a.w + w1 * b.w;
  ((float4*)(out + (size_t)t * HD))[tid] = r;
}

// ---------------- scan: counts, offsets, placement (one block) ----------------
__global__ __launch_bounds__(1024) void k_scan(const int* __restrict__ e01,
                                               const float* __restrict__ w0f,
                                               const float* __restrict__ w1f,
                                               int* __restrict__ cnt,
                                               int* __restrict__ off,
                                               int* __restrict__ gtok,
                                               float* __restrict__ gwt) {
  __shared__ int scnt[NEXPERT];
  __shared__ int soff[NEXPERT];
  __shared__ int scur[NEXPERT];
  const int t = threadIdx.x;
  if (t < NEXPERT) { scnt[t] = 0; scur[t] = 0; }
  __syncthreads();
  const int p = e01[t];
  const int e0 = p & 255, e1 = p >> 8;
  atomicAdd(&scnt[e0], 1);
  atomicAdd(&scnt[e1], 1);
  __syncthreads();
  if (t == 0) {
    int a = 0;
    for (int e = 0; e < NEXPERT; ++e) { soff[e] = a; off[e] = a; cnt[e] = scnt[e]; a += scnt[e]; }
  }
  __syncthreads();
  int s0 = atomicAdd(&scur[e0], 1);
  gtok[soff[e0] + s0] = t; gwt[soff[e0] + s0] = w0f[t];
  int s1 = atomicAdd(&scur[e1], 1);
  gtok[soff[e1] + s1] = t; gwt[soff[e1] + s1] = w1f[t];
}

// ---------------- GEMM1: 128M x 64N, 128 thr (2 waves x 64 rows), BK=32 ----------------
// Counted-vmcnt pipeline (r8, kept) + SMALLER BLOCK for 4 independent blocks/CU:
// LDS 36 KB (3-buf A 24 KB + 3-buf B 12 KB) -> 4 blk/CU, 4 independent barrier domains
// (r8 had 2 blk/CU x 4-wave groups; barriers exposed). Same traffic/instruction mix.
// Per tile per thread: 4 ldnt4 (B, 2 kblocks) + 4 async16 (A) = 8 vmem; steady wait vmcnt(8).
__global__ __launch_bounds__(128) void k_gemm1(const unsigned short* __restrict__ Xbf,
                                               const float* __restrict__ Wgu,
                                               const float* __restrict__ bgu,
                                               const int* __restrict__ cnt,
                                               const int* __restrict__ off,
                                               const int* __restrict__ gtok,
                                               unsigned short* __restrict__ Gact) {
  const int e = blockIdx.z;
  const int Ne = cnt[e];
  const int mtile = blockIdx.y;         // 0..3, 128 rows each
  if (mtile * 128 >= Ne) return;
  const int ntile = blockIdx.x;         // 0..31, 64 cols each
  const int tid = threadIdx.x;          // 0..127
  const int lane = tid & 63;
  const int wv = tid >> 6;              // 0..1 (M 64-slice)
  const int q = lane >> 4;
  const int fr = lane & 15;
  const int xq = q ^ ((fr >> 1) & 3);   // swizzled chunk/kblock index for LDS reads
  const int base = off[e] + mtile * 128;

  __shared__ unsigned short AldsL[3 * 4096];   // 3 x 128 rows x 32 shorts = 24 KB (linear, async16)
  __shared__ unsigned int BldsL[3 * 1024];     // 3 x 64 cols x 16 dwords (transposed) = 12 KB

  // A staging: thread stages rows (tid>>2) + j*32 (j=0..3); global chunk = (tid&3) ^ ((arow>>1)&3)
  // ((j*32)>>1)&3 == 0 -> swizzle j-invariant.
  const int arow = tid >> 2;
  const int cs = (tid & 3) ^ ((arow >> 1) & 3);
  const unsigned short* agp[4];
#pragma unroll
  for (int j = 0; j < 4; ++j) {
    const int r = arow + j * 32;
    const int ags = base + (((mtile * 128 + r) < Ne) ? r : 0);
    agp[j] = Xbf + (size_t)gtok[ags] * HD + cs * 8;
  }
  const int aofs = tid * 8;   // shorts (= tid*16 B); + j*1024 shorts

  // B staging: each thread handles TWO kblocks. sub=tid&3, quad=tid>>2 (0..31):
  // colgrp = quad&15, kbh = quad>>4 (0..1); kblocks {kbh, kbh+2}.
  const int sub = tid & 3;
  const int quad = tid >> 2;
  const int colgrp = quad & 15;
  const int kbh = quad >> 4;
  const int kb0 = kbh, kb1 = kbh + 2;
  const int bcol = colgrp * 4 + sub;
  const float* WbBase = Wgu + (size_t)e * HD * F2D + ntile * 64 + colgrp * 4;
  const float* Wb0 = WbBase + (size_t)(2 * (kb0 * 4 + sub)) * F2D;
  const float* Wb1 = WbBase + (size_t)(2 * (kb1 * 4 + sub)) * F2D;
  const int bofs0 = bcol * 16 + (kb0 ^ ((bcol >> 1) & 3)) * 4;
  const int bofs1 = bcol * 16 + (kb1 ^ ((bcol >> 1) & 3)) * 4;

  f32x4 acc[4][4] = {};
  fv4 b0A, b1A, c0A, c1A, b0B, b1B, c0B, c1B;   // ping-pong reg sets (2 kblocks each)

  // ---- prologue: issue tiles 0 and 1; store B0; one barrier ----
  b0A = ldnt4(Wb0); b1A = ldnt4(Wb0 + F2D);
  c0A = ldnt4(Wb1); c1A = ldnt4(Wb1 + F2D);
#pragma unroll
  for (int j = 0; j < 4; ++j)
    async16(agp[j], AldsL + aofs + j * 1024);                 // tile0 A -> buf0
  b0B = ldnt4(Wb0 + (size_t)32 * F2D); b1B = ldnt4(Wb0 + (size_t)33 * F2D);
  c0B = ldnt4(Wb1 + (size_t)32 * F2D); c1B = ldnt4(Wb1 + (size_t)33 * F2D);
#pragma unroll
  for (int j = 0; j < 4; ++j)
    async16(agp[j] + 32, AldsL + 4096 + aofs + j * 1024);     // tile1 A -> buf1
  asm volatile("s_waitcnt vmcnt(8)" ::: "memory");            // tile0's 8 done; tile1's in flight
  __builtin_amdgcn_sched_barrier(0);
  { fv4 b0 = b0A, b1 = b1A; BT_TRANSPOSE_STORE(BldsL + bofs0) }
  { fv4 b0 = c0A, b1 = c1A; BT_TRANSPOSE_STORE(BldsL + bofs1) }
  asm volatile("s_waitcnt lgkmcnt(0)" ::: "memory");
  __builtin_amdgcn_s_barrier();
  __builtin_amdgcn_sched_barrier(0);

  int cur = 0, nx1 = 1, nx2 = 2;
  for (int ks = 0; ks < 32; ++ks) {
    // 1) ds_read current tile fragments
    short8 af[4], bfr[4];
    const unsigned short* Ab = AldsL + cur * 4096;
    const unsigned int* Bb = BldsL + cur * 1024;
#pragma unroll
    for (int mi = 0; mi < 4; ++mi)
      af[mi] = *(const short8*)(Ab + (wv * 64 + mi * 16 + fr) * 32 + xq * 8);
#pragma unroll
    for (int ni = 0; ni < 4; ++ni)
      bfr[ni] = *(const short8*)(Bb + (ni * 16 + fr) * 16 + xq * 4);
    // 2) issue tile ks+2 loads (B -> regs[ks&1], A -> LDS buf nx2)
    if (ks < 30) {
      const size_t ko = (size_t)(ks + 2) * 32 * F2D;
      if ((ks & 1) == 0) {
        b0A = ldnt4(Wb0 + ko); b1A = ldnt4(Wb0 + ko + F2D);
        c0A = ldnt4(Wb1 + ko); c1A = ldnt4(Wb1 + ko + F2D);
      } else {
        b0B = ldnt4(Wb0 + ko); b1B = ldnt4(Wb0 + ko + F2D);
        c0B = ldnt4(Wb1 + ko); c1B = ldnt4(Wb1 + ko + F2D);
      }
      unsigned short* Adst = AldsL + nx2 * 4096 + aofs;
#pragma unroll
      for (int j = 0; j < 4; ++j)
        async16(agp[j] + (ks + 2) * 32, Adst + j * 1024);
    }
    // 3) MFMA on current tile
#pragma unroll
    for (int mi = 0; mi < 4; ++mi)
#pragma unroll
      for (int ni = 0; ni < 4; ++ni)
        acc[mi][ni] = __builtin_amdgcn_mfma_f32_16x16x32_bf16(af[mi], bfr[ni], acc[mi][ni], 0, 0, 0);
    // 4) counted wait: tile ks+1's 8 ops done (ks+2's stay in flight); store B(ks+1)
    if (ks < 30) {
      asm volatile("s_waitcnt vmcnt(8)" ::: "memory");
      __builtin_amdgcn_sched_barrier(0);
    } else if (ks == 30) {
      asm volatile("s_waitcnt vmcnt(0)" ::: "memory");
      __builtin_amdgcn_sched_barrier(0);
    }
    if (ks < 31) {
      // store from regs[(ks+1)&1]: ks even -> B-regs, ks odd -> A-regs
      if (ks & 1) {
        { fv4 b0 = b0A, b1 = b1A; BT_TRANSPOSE_STORE(BldsL + nx1 * 1024 + bofs0) }
        { fv4 b0 = c0A, b1 = c1A; BT_TRANSPOSE_STORE(BldsL + nx1 * 1024 + bofs1) }
      } else {
        { fv4 b0 = b0B, b1 = b1B; BT_TRANSPOSE_STORE(BldsL + nx1 * 1024 + bofs0) }
        { fv4 b0 = c0B, b1 = c1B; BT_TRANSPOSE_STORE(BldsL + nx1 * 1024 + bofs1) }
      }
      asm volatile("s_waitcnt lgkmcnt(0)" ::: "memory");
      __builtin_amdgcn_s_barrier();
      __builtin_amdgcn_sched_barrier(0);
    }
    const int tmp = cur; cur = nx1; nx1 = nx2; nx2 = tmp;
  }

  // epilogue: +bgu, de-interleave gate/up via lane-pair shuffle, activation, store bf16
  const float* bguE = bgu + (size_t)e * F2D + ntile * 64;
#pragma unroll
  for (int mi = 0; mi < 4; ++mi) {
#pragma unroll
    for (int ni = 0; ni < 4; ++ni) {
      const int coll = ni * 16 + fr;
      const float bias = bguE[coll];
#pragma unroll
      for (int r = 0; r < 4; ++r) {
        const int srow = wv * 64 + mi * 16 + q * 4 + r;
        float v = acc[mi][ni][r] + bias;
        float pv = __shfl_xor(v, 1);
        float gate = (lane & 1) ? pv : v;   // even f2-cols are gate, odd are up
        float up   = (lane & 1) ? v : pv;
        gate = fminf(gate, LIMIT_C);
        up = fminf(fmaxf(up, -LIMIT_C), LIMIT_C);
        float glu = gate / (1.f + __expf(-ALPHA_C * gate));
        float val = (up + 1.f) * glu;
        if (!(lane & 1) && (mtile * 128 + srow) < Ne)
          Gact[(size_t)(base + srow) * ED + ((ntile * 64 + coll) >> 1)] = f2bf(val);
      }
    }
  }
}

// ---------------- GEMM2: round-4 proven config: block 256M x 64N, 512 thr, BK=32, dbuf ----------------
#define BSTG2T 20
__global__ __launch_bounds__(512, 2) void k_gemm2(const unsigned short* __restrict__ Gact,
                                                  const float* __restrict__ Wd,
                                                  const int* __restrict__ cnt,
                                                  const int* __restrict__ off,
                                                  const int* __restrict__ gtok,
                                                  const float* __restrict__ gwt,
                                                  float* __restrict__ out) {
  const int e = blockIdx.z;
  const int Ne = cnt[e];
  const int mtile = blockIdx.y;
  if (mtile * 256 >= Ne) return;
  const int ntile = blockIdx.x;
  const int tid = threadIdx.x;          // 0..511
  const int lane = tid & 63;
  const int wv = tid >> 6;              // 0..7 (M 32-slice; N full 64)
  const int q = lane >> 4;
  const int fr = lane & 15;
  const int base = off[e] + mtile * 256;

  __shared__ unsigned short Alds[2][256 * 32];     // 32 KB
  __shared__ unsigned int Blds[2][64 * BSTG2T];    // transposed B, ~10.2 KB

  const int ar0 = wv * 32 + (lane >> 2);
  const unsigned short* agp0 = Gact + (size_t)(base + ar0) * ED + (lane & 3) * 8;
  const unsigned short* agp1 = agp0 + (size_t)16 * ED;
  const int aofs = wv * 1024;

  const int sub = lane & 3;
  const float* Wb = Wd + (size_t)e * ED * HD + (size_t)(2 * (wv * 4 + sub)) * HD + ntile * 64 + (lane >> 2) * 4;
  const int bofs = lane * BSTG2T + wv * 4;

  f32x4 acc[2][4] = {};
  fv4 b0, b1;

  if (tid < 256) {
    b0 = ldnt4(Wb);
    b1 = ldnt4(Wb + HD);
  }
  async16(agp0, Alds[0] + aofs);
  async16(agp1, Alds[0] + aofs + 512);
  if (tid < 256) BT_TRANSPOSE_STORE(Blds[0] + bofs)
  __syncthreads();

  for (int ks = 0; ks < 32; ++ks) {
    const int cur = ks & 1, nxt = cur ^ 1;
    const bool more = (ks + 1) < 32;
    if (more) {
      if (tid < 256) {
        const float* bp = Wb + (size_t)(ks + 1) * 32 * HD;
        b0 = ldnt4(bp);
        b1 = ldnt4(bp + HD);
      }
      async16(agp0 + (ks + 1) * 32, Alds[nxt] + aofs);
      async16(agp1 + (ks + 1) * 32, Alds[nxt] + aofs + 512);
    }
    short8 af[2], bfr[4];
#pragma unroll
    for (int mi = 0; mi < 2; ++mi)
      af[mi] = *(const short8*)(Alds[cur] + (wv * 32 + mi * 16 + fr) * 32 + q * 8);
#pragma unroll
    for (int ni = 0; ni < 4; ++ni)
      bfr[ni] = *(const short8*)(Blds[cur] + (ni * 16 + fr) * BSTG2T + q * 4);
#pragma unroll
    for (int mi = 0; mi < 2; ++mi)
#pragma unroll
      for (int ni = 0; ni < 4; ++ni)
        acc[mi][ni] = __builtin_amdgcn_mfma_f32_16x16x32_bf16(af[mi], bfr[ni], acc[mi][ni], 0, 0, 0);
    if (more && tid < 256) BT_TRANSPOSE_STORE(Blds[nxt] + bofs)
    __syncthreads();
  }

#pragma unroll
  for (int mi = 0; mi < 2; ++mi) {
#pragma unroll
    for (int r = 0; r < 4; ++r) {
      const int srow = wv * 32 + mi * 16 + q * 4 + r;
      if ((mtile * 256 + srow) < Ne) {
        const int gsl = base + srow;
        const int tok = gtok[gsl];
        const float wt = gwt[gsl];
        float* op = out + (size_t)tok * HD + ntile * 64;
#pragma unroll
        for (int ni = 0; ni < 4; ++ni) {
          const int col = ni * 16 + fr;
          atomicAdd(op + col, wt * acc[mi][ni][r]);
        }
      }
    }
  }
}

extern "C" void kernel_launch(void* const* d_in, const int* in_sizes, int n_in,
                              void* d_out, int out_size, void* d_ws, size_t ws_size,
                              hipStream_t stream) {
  const float* x   = (const float*)d_in[0];
  const float* Wg  = (const float*)d_in[1];
  const float* bg  = (const float*)d_in[2];
  const float* Wgu = (const float*)d_in[3];
  const float* bgu = (const float*)d_in[4];
  const float* Wd  = (const float*)d_in[5];
  const float* bd  = (const float*)d_in[6];
  float* out = (float*)d_out;

  int* cnt = (int*)d_ws;                    // 16
  int* off = cnt + 16;                      // 16
  int* e01 = off + 16;                      // 1024
  float* w0f = (float*)(e01 + NT);          // 1024
  float* w1f = w0f + NT;                    // 1024
  int* gtok = (int*)(w1f + NT);             // GROWS
  float* gwt = (float*)(gtok + GROWS);      // GROWS
  unsigned short* Xbf = (unsigned short*)(gwt + GROWS);        // NT*HD bf16
  unsigned short* Gact = Xbf + (size_t)NT * HD;                // GROWS*ED bf16

  k_router<<<NT, 256, 0, stream>>>(x, Wg, bg, bd, e01, w0f, w1f, Xbf, out);
  k_scan<<<1, NT, 0, stream>>>(e01, w0f, w1f, cnt, off, gtok, gwt);
  k_gemm1<<<dim3(32, 4, NEXPERT), 128, 0, stream>>>(Xbf, Wgu, bgu, cnt, off, gtok, Gact);
  k_gemm2<<<dim3(16, 2, NEXPERT), 512, 0, stream>>>(Gact, Wd, cnt, off, gtok, gwt, out);
}